// Round 11
// baseline (1020.209 us; speedup 1.0000x reference)
//
#include <hip/hip_runtime.h>

#define NTOK 49
#define CDIM 384
#define HEADS 12
#define HD 32
#define NWIN 64
#define NQKV 1152
#define SCALE 0.17677669529663687f  // 32^-0.5

typedef __attribute__((ext_vector_type(8))) __bf16 bf16x8;
typedef __attribute__((ext_vector_type(4))) float f32x4;

// workspace offsets (bytes), all 256-aligned
#define OFF_WQKVT   0ull                 // 1152*384 bf16 = 884736
#define OFF_WOUTT   884736ull            // 384*384 bf16  = 294912
#define OFF_ADDEND  1179648ull           // 64*12*49*49 f32 = 7375872
#define OFF_QKVB    8555520ull           // 200704*1152 bf16 = 462422016
#define OFF_ATTNOUT 470977536ull         // 200704*384 bf16 = 154140672
// total ~625.1 MB

__device__ __forceinline__ void async_copy16(__bf16* lds_dst, const __bf16* g_src) {
    __builtin_amdgcn_global_load_lds(
        (const __attribute__((address_space(1))) void*)g_src,
        (__attribute__((address_space(3))) void*)lds_dst,
        16, 0, 0);
}

// ---------------- prep kernels ----------------

__global__ void prep_weights(const float* __restrict__ Wqkv, const float* __restrict__ Wout,
                             __bf16* __restrict__ WqkvT, __bf16* __restrict__ WoutT) {
    int idx = blockIdx.x * 256 + threadIdx.x;
    if (idx < NQKV * CDIM) {
        int n = idx / CDIM, k = idx % CDIM;
        WqkvT[idx] = (__bf16)Wqkv[(size_t)k * NQKV + n];
    }
    if (idx < CDIM * CDIM) {
        int n = idx / CDIM, k = idx % CDIM;
        WoutT[idx] = (__bf16)Wout[(size_t)k * CDIM + n];
    }
}

__global__ void prep_addend(const float* __restrict__ rpb, const int* __restrict__ rel,
                            const float* __restrict__ mask, float* __restrict__ addend) {
    int idx = blockIdx.x * 256 + threadIdx.x;
    if (idx >= NWIN * HEADS * NTOK * NTOK) return;
    int mn = idx % (NTOK * NTOK);
    int h  = (idx / (NTOK * NTOK)) % HEADS;
    int w  = idx / (NTOK * NTOK * HEADS);
    addend[idx] = rpb[rel[mn] * HEADS + h] + mask[(size_t)w * NTOK * NTOK + mn];
}

// ---------------- K1: qkv GEMM, m97 structure + XCD swizzle + fused fp32->bf16 A-staging ----------------
// [M=200704,384] @ [384,1152] -> qkvb bf16 [M][1152]. 1D grid 14112 blocks.
// A staged from x (fp32) via reg: 2x float4 load -> cvt -> ds_write_b128 (same frag-linear layout);
// B staged via global_load_lds(16B). Replaces the separate prep_xb pass (saves 462MB kernel).

__global__ __launch_bounds__(256, 3) void gemm_qkv(
    const float* __restrict__ x, const __bf16* __restrict__ WqkvT,
    const float* __restrict__ bqkv, __bf16* __restrict__ qkvb)
{
    __shared__ __attribute__((aligned(16))) __bf16 smem[16384];  // A [0,8192), B [8192,16384); C overlays
    __bf16* As = smem;
    __bf16* Bs = smem + 8192;

    // bijective XCD-chunk swizzle: nwg = 14112 = 8 * 1764
    const int cpx  = 14112 >> 3;                     // 1764
    const int lid  = (blockIdx.x & 7) * cpx + (blockIdx.x >> 3);
    const int mblk = lid / 9, nblk = lid % 9;
    const int n0  = nblk * 128;
    const int bm0 = mblk * 128;

    const int tid = threadIdx.x;
    const int wave = tid >> 6, lane = tid & 63;
    const int l15 = lane & 15, l4 = lane >> 4;
    const int wr = wave >> 1, wc = wave & 1;

    f32x4 acc[4][4] = {};

    for (int k0 = 0; k0 < CDIM; k0 += 64) {
        // B: async global->LDS (4 chunks per wave)
#pragma unroll
        for (int j = 0; j < 4; ++j) {
            int c = wave * 4 + j;
            int mt = c >> 1, kk = c & 1;
            const __bf16* sb = WqkvT + (size_t)(n0 + mt * 16 + l15) * CDIM + k0 + kk * 32 + l4 * 8;
            async_copy16(&Bs[c * 512], sb);
        }
        // A: reg-staged fp32 -> bf16 (4 chunks per wave, same frag-linear addresses)
#pragma unroll
        for (int j = 0; j < 4; ++j) {
            int c = wave * 4 + j;
            int mt = c >> 1, kk = c & 1;
            const float* sa = x + (size_t)(bm0 + mt * 16 + l15) * CDIM + k0 + kk * 32 + l4 * 8;
            float4 a0 = reinterpret_cast<const float4*>(sa)[0];
            float4 a1 = reinterpret_cast<const float4*>(sa)[1];
            union { __bf16 h[8]; int4 u; } t;
            t.h[0] = (__bf16)a0.x; t.h[1] = (__bf16)a0.y; t.h[2] = (__bf16)a0.z; t.h[3] = (__bf16)a0.w;
            t.h[4] = (__bf16)a1.x; t.h[5] = (__bf16)a1.y; t.h[6] = (__bf16)a1.z; t.h[7] = (__bf16)a1.w;
            *reinterpret_cast<int4*>(&As[c * 512 + lane * 8]) = t.u;
        }
        __syncthreads();   // drains lgkm (A ds_writes) + vm (B gload_lds)

#pragma unroll
        for (int kk = 0; kk < 2; ++kk) {
            bf16x8 af[4], bf[4];
#pragma unroll
            for (int mi = 0; mi < 4; ++mi)
                af[mi] = *reinterpret_cast<const bf16x8*>(&As[((wr * 4 + mi) * 2 + kk) * 512 + lane * 8]);
#pragma unroll
            for (int ni = 0; ni < 4; ++ni)
                bf[ni] = *reinterpret_cast<const bf16x8*>(&Bs[((wc * 4 + ni) * 2 + kk) * 512 + lane * 8]);
#pragma unroll
            for (int mi = 0; mi < 4; ++mi)
#pragma unroll
                for (int ni = 0; ni < 4; ++ni)
                    acc[mi][ni] = __builtin_amdgcn_mfma_f32_16x16x32_bf16(af[mi], bf[ni], acc[mi][ni], 0, 0, 0);
        }
        __syncthreads();   // compute reads done before next stage overwrites
    }

    const float scl = (n0 < CDIM) ? SCALE : 1.0f;
    float bias[4];
#pragma unroll
    for (int ni = 0; ni < 4; ++ni)
        bias[ni] = bqkv[n0 + wc * 64 + ni * 16 + l15];

    __bf16* Cs = smem;   // [128][128] bf16, byte ^= ((row>>2)&3)<<5
#pragma unroll
    for (int mi = 0; mi < 4; ++mi)
#pragma unroll
        for (int ni = 0; ni < 4; ++ni)
#pragma unroll
            for (int r = 0; r < 4; ++r) {
                int row = wr * 64 + mi * 16 + l4 * 4 + r;
                int col = wc * 64 + ni * 16 + l15;
                int byte = (row * 256 + col * 2) ^ (((row >> 2) & 3) << 5);
                *reinterpret_cast<__bf16*>(reinterpret_cast<char*>(Cs) + byte) =
                    (__bf16)((acc[mi][ni][r] + bias[ni]) * scl);
            }
    __syncthreads();

#pragma unroll
    for (int it = 0; it < 8; ++it) {
        int idx = it * 4096 + tid * 16;
        int row = idx >> 8, bcol = idx & 255;
        int sb = (row * 256 + bcol) ^ (((row >> 2) & 3) << 5);
        uint4 v = *reinterpret_cast<const uint4*>(reinterpret_cast<const char*>(Cs) + sb);
        *reinterpret_cast<uint4*>(reinterpret_cast<char*>(&qkvb[(size_t)(bm0 + row) * NQKV + n0]) + bcol) = v;
    }
}

// ---------------- K2: attention (unchanged from r10) ----------------
// grid (B, 3): 256 thr = 4 waves; wave = one head. No barriers.
// V: 4 coalesced 16B loads/lane -> wave-private LDS [d][tok] (d-XOR swizzled) -> ds_read_b128 frags.

__global__ __launch_bounds__(256) void attn(
    const __bf16* __restrict__ qkvb, const float* __restrict__ addend,
    __bf16* __restrict__ attnout)
{
    __shared__ __attribute__((aligned(16))) __bf16 vt[4][32 * 64];    // [wave][d][tok ^ ((d&7)<<3)] 4KB/wave
    __shared__ __attribute__((aligned(16))) __bf16 ps[4][2][64][8];   // [wave][kb][lane][8]
    const int b = blockIdx.x;
    const int tid = threadIdx.x;
    const int wave = tid >> 6, lane = tid & 63;
    const int l15 = lane & 15, l4 = lane >> 4;
    const int h = blockIdx.y * 4 + wave;
    const int w = b & (NWIN - 1);

    const __bf16* base = qkvb + (size_t)b * NTOK * NQKV;

    // ---- stage V coalesced: lane loads v[tok][c8..c8+7], scatters transposed into vt ----
    {
        const int tokb = lane >> 2;         // 0..15
        const int c8   = (lane & 3) * 8;    // 0,8,16,24
#pragma unroll
        for (int i = 0; i < 4; ++i) {
            int tok = i * 16 + tokb;
            bf16x8 vv = *reinterpret_cast<const bf16x8*>(base + (size_t)tok * NQKV + 2 * CDIM + h * HD + c8);
#pragma unroll
            for (int j = 0; j < 8; ++j) {
                int d = c8 + j;
                vt[wave][d * 64 + (tok ^ ((d & 7) << 3))] = vv[j];
            }
        }
    }

    bf16x8 kf[4];
#pragma unroll
    for (int nt = 0; nt < 4; ++nt)
        kf[nt] = *reinterpret_cast<const bf16x8*>(base + (size_t)(nt * 16 + l15) * NQKV + CDIM + h * HD + l4 * 8);

    const float* add_h = addend + (size_t)(w * HEADS + h) * (NTOK * NTOK);

    for (int mt = 0; mt < 4; ++mt) {
        bf16x8 qf = *reinterpret_cast<const bf16x8*>(base + (size_t)(mt * 16 + l15) * NQKV + h * HD + l4 * 8);
        f32x4 s[4];
#pragma unroll
        for (int nt = 0; nt < 4; ++nt) {
            f32x4 z = {};
            s[nt] = __builtin_amdgcn_mfma_f32_16x16x32_bf16(qf, kf[nt], z, 0, 0, 0);
        }

#pragma unroll
        for (int r = 0; r < 4; ++r) {
            int m = mt * 16 + l4 * 4 + r;
            float vals[4];
#pragma unroll
            for (int nt = 0; nt < 4; ++nt) {
                int n = nt * 16 + l15;
                float sv = s[nt][r];
                if (n < NTOK) {
                    if (m < NTOK) sv += add_h[m * NTOK + n];
                } else {
                    sv = -1e30f;
                }
                vals[nt] = sv;
            }
            float mx = fmaxf(fmaxf(vals[0], vals[1]), fmaxf(vals[2], vals[3]));
            mx = fmaxf(mx, __shfl_xor(mx, 1));
            mx = fmaxf(mx, __shfl_xor(mx, 2));
            mx = fmaxf(mx, __shfl_xor(mx, 4));
            mx = fmaxf(mx, __shfl_xor(mx, 8));
            float e0 = __expf(vals[0] - mx);
            float e1 = __expf(vals[1] - mx);
            float e2 = __expf(vals[2] - mx);
            float e3 = __expf(vals[3] - mx);
            float sum = (e0 + e1) + (e2 + e3);
            sum += __shfl_xor(sum, 1);
            sum += __shfl_xor(sum, 2);
            sum += __shfl_xor(sum, 4);
            sum += __shfl_xor(sum, 8);
            float inv = 1.0f / sum;
            float ev[4] = {e0, e1, e2, e3};
#pragma unroll
            for (int nt = 0; nt < 4; ++nt) {
                int lp = (l4 * 4 + r) + 16 * ((nt & 1) * 2 + (l15 >> 3));
                ps[wave][nt >> 1][lp][l15 & 7] = (__bf16)(ev[nt] * inv);
            }
        }

        f32x4 o[2] = {};
#pragma unroll
        for (int kb = 0; kb < 2; ++kb) {
            bf16x8 ap = *reinterpret_cast<const bf16x8*>(&ps[wave][kb][lane][0]);
#pragma unroll
            for (int dt = 0; dt < 2; ++dt) {
                int d = dt * 16 + l15;
                bf16x8 bv = *reinterpret_cast<const bf16x8*>(
                    &vt[wave][d * 64 + ((kb * 32 + l4 * 8) ^ ((l15 & 7) << 3))]);
                o[dt] = __builtin_amdgcn_mfma_f32_16x16x32_bf16(ap, bv, o[dt], 0, 0, 0);
            }
        }
#pragma unroll
        for (int dt = 0; dt < 2; ++dt) {
            int col = h * HD + dt * 16 + l15;
#pragma unroll
            for (int r = 0; r < 4; ++r) {
                int tok = mt * 16 + l4 * 4 + r;
                if (tok < NTOK)
                    attnout[((size_t)b * NTOK + tok) * CDIM + col] = (__bf16)o[dt][r];
            }
        }
    }
}

// ---------------- K3: out projection (unchanged) ----------------

__global__ __launch_bounds__(256, 3) void out_proj(
    const __bf16* __restrict__ A, const __bf16* __restrict__ WoutT,
    const float* __restrict__ bout, float* __restrict__ out)
{
    __shared__ __attribute__((aligned(16))) __bf16 as[4 * 12 * 512];   // frags [mt][kb][slot][8]
    const int blk = blockIdx.x, tid = threadIdx.x;
    const int wave = tid >> 6, lane = tid & 63;
    const int l15 = lane & 15, l4 = lane >> 4;

    const __bf16* Ab = A + (size_t)blk * 64 * CDIM;
    for (int i = tid; i < 64 * CDIM / 8; i += 256) {
        int4 ld = reinterpret_cast<const int4*>(Ab)[i];
        int e = i * 8;
        int row = e / CDIM, c = e % CDIM;
        int mt = row >> 4, kb = c >> 5;
        int lp = (row & 15) + 16 * ((c & 31) >> 3);
        int slot = lp ^ (kb & 7);
        *reinterpret_cast<int4*>(&as[((mt * 12 + kb) * 64 + slot) * 8]) = ld;
    }
    __syncthreads();

    f32x4 acc[6][4] = {};
    for (int kb = 0; kb < 12; ++kb) {
        int slot = lane ^ (kb & 7);
        bf16x8 af[4];
#pragma unroll
        for (int mt = 0; mt < 4; ++mt)
            af[mt] = *reinterpret_cast<const bf16x8*>(&as[((mt * 12 + kb) * 64 + slot) * 8]);
#pragma unroll
        for (int j = 0; j < 6; ++j) {
            int col = (wave * 6 + j) * 16 + l15;
            bf16x8 bf = *reinterpret_cast<const bf16x8*>(WoutT + (size_t)col * CDIM + kb * 32 + l4 * 8);
#pragma unroll
            for (int mt = 0; mt < 4; ++mt)
                acc[j][mt] = __builtin_amdgcn_mfma_f32_16x16x32_bf16(af[mt], bf, acc[j][mt], 0, 0, 0);
        }
    }
#pragma unroll
    for (int j = 0; j < 6; ++j) {
        int col = (wave * 6 + j) * 16 + l15;
        float bias = bout[col];
#pragma unroll
        for (int mt = 0; mt < 4; ++mt) {
#pragma unroll
            for (int r = 0; r < 4; ++r) {
                size_t row = (size_t)blk * 64 + mt * 16 + l4 * 4 + r;
                out[row * CDIM + col] = acc[j][mt][r] + bias;
            }
        }
    }
}

// ---------------- launch ----------------

extern "C" void kernel_launch(void* const* d_in, const int* in_sizes, int n_in,
                              void* d_out, int out_size, void* d_ws, size_t ws_size,
                              hipStream_t stream) {
    (void)n_in; (void)out_size; (void)ws_size;
    const float* x    = (const float*)d_in[0];
    const float* mask = (const float*)d_in[1];
    const float* Wqkv = (const float*)d_in[2];
    const float* bqkv = (const float*)d_in[3];
    const float* Wout = (const float*)d_in[4];
    const float* bout = (const float*)d_in[5];
    const float* rpb  = (const float*)d_in[6];
    const int*   rel  = (const int*)d_in[7];

    const int B = in_sizes[0] / (NTOK * CDIM);   // 4096
    const int M = B * NTOK;                      // 200704

    char* ws = (char*)d_ws;
    __bf16* WqkvT   = (__bf16*)(ws + OFF_WQKVT);
    __bf16* WoutT   = (__bf16*)(ws + OFF_WOUTT);
    float*  addend  = (float*)(ws + OFF_ADDEND);
    __bf16* qkvb    = (__bf16*)(ws + OFF_QKVB);
    __bf16* attnout = (__bf16*)(ws + OFF_ATTNOUT);
    float*  out     = (float*)d_out;

    prep_weights<<<(NQKV * CDIM + 255) / 256, 256, 0, stream>>>(Wqkv, Wout, WqkvT, WoutT);
    prep_addend<<<(NWIN * HEADS * NTOK * NTOK + 255) / 256, 256, 0, stream>>>(rpb, rel, mask, addend);
    gemm_qkv<<<(M / 128) * (NQKV / 128), 256, 0, stream>>>(x, WqkvT, bqkv, qkvb);
    attn<<<dim3(B, 3), 256, 0, stream>>>(qkvb, addend, attnout);
    out_proj<<<M / 64, 256, 0, stream>>>(attnout, WoutT, bout, out);
}

// Round 12
// 927.334 us; speedup vs baseline: 1.1002x; 1.1002x over previous
//
#include <hip/hip_runtime.h>

#define NTOK 49
#define CDIM 384
#define HEADS 12
#define HD 32
#define NWIN 64
#define NQKV 1152
#define SCALE 0.17677669529663687f  // 32^-0.5

typedef __attribute__((ext_vector_type(8))) __bf16 bf16x8;
typedef __attribute__((ext_vector_type(4))) float f32x4;

// workspace offsets (bytes), all 256-aligned
#define OFF_WQKVT   0ull                 // 1152*384 bf16 = 884736
#define OFF_WOUTT   884736ull            // 384*384 bf16  = 294912
#define OFF_ADDEND  1179648ull           // 64*12*49*49 f32 = 7375872
#define OFF_QKVB    8555520ull           // 3 tensors [B][12][49][32] bf16 = 462422016 total
#define OFF_ATTNOUT 470977536ull         // 200704*384 bf16 = 154140672
#define OFF_XB      OFF_ATTNOUT          // xb aliases attnout: xb dead before attn writes
// total ~625.1 MB

#define TSIZE 77070336ull                // per-tensor elems: 200704*384 = B*HEADS*NTOK*HD

__device__ __forceinline__ void async_copy16(__bf16* lds_dst, const __bf16* g_src) {
    __builtin_amdgcn_global_load_lds(
        (const __attribute__((address_space(1))) void*)g_src,
        (__attribute__((address_space(3))) void*)lds_dst,
        16, 0, 0);
}

// ---------------- prep kernels ----------------

__global__ void prep_weights(const float* __restrict__ Wqkv, const float* __restrict__ Wout,
                             __bf16* __restrict__ WqkvT, __bf16* __restrict__ WoutT) {
    int idx = blockIdx.x * 256 + threadIdx.x;
    if (idx < NQKV * CDIM) {
        int n = idx / CDIM, k = idx % CDIM;
        WqkvT[idx] = (__bf16)Wqkv[(size_t)k * NQKV + n];
    }
    if (idx < CDIM * CDIM) {
        int n = idx / CDIM, k = idx % CDIM;
        WoutT[idx] = (__bf16)Wout[(size_t)k * CDIM + n];
    }
}

__global__ void prep_addend(const float* __restrict__ rpb, const int* __restrict__ rel,
                            const float* __restrict__ mask, float* __restrict__ addend) {
    int idx = blockIdx.x * 256 + threadIdx.x;
    if (idx >= NWIN * HEADS * NTOK * NTOK) return;
    int mn = idx % (NTOK * NTOK);
    int h  = (idx / (NTOK * NTOK)) % HEADS;
    int w  = idx / (NTOK * NTOK * HEADS);
    addend[idx] = rpb[rel[mn] * HEADS + h] + mask[(size_t)w * NTOK * NTOK + mn];
}

// x fp32 -> bf16, streaming (8 elems / thread / iter)
__global__ __launch_bounds__(256) void prep_xb(const float* __restrict__ x,
                                               __bf16* __restrict__ xb, int total8) {
    int stride = gridDim.x * 256;
    for (int i = blockIdx.x * 256 + threadIdx.x; i < total8; i += stride) {
        float4 a = reinterpret_cast<const float4*>(x)[i * 2];
        float4 b = reinterpret_cast<const float4*>(x)[i * 2 + 1];
        union { __bf16 h[8]; uint4 u; } t;
        t.h[0] = (__bf16)a.x; t.h[1] = (__bf16)a.y; t.h[2] = (__bf16)a.z; t.h[3] = (__bf16)a.w;
        t.h[4] = (__bf16)b.x; t.h[5] = (__bf16)b.y; t.h[6] = (__bf16)b.z; t.h[7] = (__bf16)b.w;
        reinterpret_cast<uint4*>(xb)[i] = t.u;
    }
}

// ---------------- K1: qkv GEMM, m97 structure + XCD swizzle; head-blocked output ----------------
// [M=200704,384] @ [384,1152]. Output: 3 tensors q/k/v each [b][h][49][32] bf16 (head-blocked),
// so attn reads are fully contiguous per head. Epilogue scatters 16B chunks (64B head-rows).

__global__ __launch_bounds__(256, 3) void gemm_qkv(
    const __bf16* __restrict__ xb, const __bf16* __restrict__ WqkvT,
    const float* __restrict__ bqkv, __bf16* __restrict__ qkvb)
{
    __shared__ __attribute__((aligned(16))) __bf16 smem[16384];  // A [0,8192), B [8192,16384); C overlays
    __bf16* As = smem;
    __bf16* Bs = smem + 8192;

    // bijective XCD-chunk swizzle: nwg = 14112 = 8 * 1764
    const int cpx  = 14112 >> 3;                     // 1764
    const int lid  = (blockIdx.x & 7) * cpx + (blockIdx.x >> 3);
    const int mblk = lid / 9, nblk = lid % 9;
    const int n0  = nblk * 128;
    const int bm0 = mblk * 128;

    const int tid = threadIdx.x;
    const int wave = tid >> 6, lane = tid & 63;
    const int l15 = lane & 15, l4 = lane >> 4;
    const int wr = wave >> 1, wc = wave & 1;

    f32x4 acc[4][4] = {};

    for (int k0 = 0; k0 < CDIM; k0 += 64) {
#pragma unroll
        for (int j = 0; j < 4; ++j) {
            int c = wave * 4 + j;
            int mt = c >> 1, kk = c & 1;
            const __bf16* sa = xb + (size_t)(bm0 + mt * 16 + l15) * CDIM + k0 + kk * 32 + l4 * 8;
            async_copy16(&As[c * 512], sa);
            const __bf16* sb = WqkvT + (size_t)(n0 + mt * 16 + l15) * CDIM + k0 + kk * 32 + l4 * 8;
            async_copy16(&Bs[c * 512], sb);
        }
        __syncthreads();

#pragma unroll
        for (int kk = 0; kk < 2; ++kk) {
            bf16x8 af[4], bf[4];
#pragma unroll
            for (int mi = 0; mi < 4; ++mi)
                af[mi] = *reinterpret_cast<const bf16x8*>(&As[((wr * 4 + mi) * 2 + kk) * 512 + lane * 8]);
#pragma unroll
            for (int ni = 0; ni < 4; ++ni)
                bf[ni] = *reinterpret_cast<const bf16x8*>(&Bs[((wc * 4 + ni) * 2 + kk) * 512 + lane * 8]);
#pragma unroll
            for (int mi = 0; mi < 4; ++mi)
#pragma unroll
                for (int ni = 0; ni < 4; ++ni)
                    acc[mi][ni] = __builtin_amdgcn_mfma_f32_16x16x32_bf16(af[mi], bf[ni], acc[mi][ni], 0, 0, 0);
        }
        __syncthreads();
    }

    const float scl = (n0 < CDIM) ? SCALE : 1.0f;
    float bias[4];
#pragma unroll
    for (int ni = 0; ni < 4; ++ni)
        bias[ni] = bqkv[n0 + wc * 64 + ni * 16 + l15];

    __bf16* Cs = smem;   // [128][128] bf16, byte ^= ((row>>2)&3)<<5
#pragma unroll
    for (int mi = 0; mi < 4; ++mi)
#pragma unroll
        for (int ni = 0; ni < 4; ++ni)
#pragma unroll
            for (int r = 0; r < 4; ++r) {
                int row = wr * 64 + mi * 16 + l4 * 4 + r;
                int col = wc * 64 + ni * 16 + l15;
                int byte = (row * 256 + col * 2) ^ (((row >> 2) & 3) << 5);
                *reinterpret_cast<__bf16*>(reinterpret_cast<char*>(Cs) + byte) =
                    (__bf16)((acc[mi][ni][r] + bias[ni]) * scl);
            }
    __syncthreads();

    // head-blocked scatter: tensor = n0/384; 128 cols = 4 heads h0..h0+3
    const int which = n0 / CDIM;
    const int h0    = (n0 % CDIM) >> 5;
    __bf16* tbase = qkvb + (size_t)which * TSIZE;
#pragma unroll
    for (int it = 0; it < 8; ++it) {
        int idx = it * 4096 + tid * 16;
        int row = idx >> 8, bcol = idx & 255;
        int sb = (row * 256 + bcol) ^ (((row >> 2) & 3) << 5);
        uint4 v = *reinterpret_cast<const uint4*>(reinterpret_cast<const char*>(Cs) + sb);
        int grow = bm0 + row;
        int b = grow / NTOK, tok = grow - b * NTOK;
        int col = bcol >> 1;                 // 0..127
        int h = h0 + (col >> 5), d = col & 31;
        *reinterpret_cast<uint4*>(&tbase[(((size_t)b * HEADS + h) * NTOK + tok) * HD + d]) = v;
    }
}

// ---------------- K2: attention (head-blocked reads; V via wave-private LDS) ----------------
// grid (B, 3): 256 thr = 4 waves; wave = one head. No barriers.
// All q/k/v fragment loads are 1KB-contiguous per instruction now.

__global__ __launch_bounds__(256) void attn(
    const __bf16* __restrict__ qkvb, const float* __restrict__ addend,
    __bf16* __restrict__ attnout)
{
    __shared__ __attribute__((aligned(16))) __bf16 vt[4][32 * 64];    // [wave][d][tok ^ ((d&7)<<3)] 4KB/wave
    __shared__ __attribute__((aligned(16))) __bf16 ps[4][2][64][8];   // [wave][kb][lane][8]
    const int b = blockIdx.x;
    const int tid = threadIdx.x;
    const int wave = tid >> 6, lane = tid & 63;
    const int l15 = lane & 15, l4 = lane >> 4;
    const int h = blockIdx.y * 4 + wave;
    const int w = b & (NWIN - 1);

    const size_t hoff = (((size_t)b * HEADS + h) * NTOK) * HD;
    const __bf16* qb = qkvb + hoff;
    const __bf16* kb = qkvb + TSIZE + hoff;
    const __bf16* vb = qkvb + 2 * TSIZE + hoff;

    // ---- stage V coalesced: lane loads v[tok][c8..c8+7], scatters transposed into vt ----
    {
        const int tokb = lane >> 2;         // 0..15
        const int c8   = (lane & 3) * 8;    // 0,8,16,24
#pragma unroll
        for (int i = 0; i < 4; ++i) {
            int tok = i * 16 + tokb;
            bf16x8 vv = *reinterpret_cast<const bf16x8*>(vb + (size_t)tok * HD + c8);
#pragma unroll
            for (int j = 0; j < 8; ++j) {
                int d = c8 + j;
                vt[wave][d * 64 + (tok ^ ((d & 7) << 3))] = vv[j];
            }
        }
    }

    bf16x8 kf[4];
#pragma unroll
    for (int nt = 0; nt < 4; ++nt)
        kf[nt] = *reinterpret_cast<const bf16x8*>(kb + (size_t)(nt * 16 + l15) * HD + l4 * 8);

    const float* add_h = addend + (size_t)(w * HEADS + h) * (NTOK * NTOK);

    for (int mt = 0; mt < 4; ++mt) {
        bf16x8 qf = *reinterpret_cast<const bf16x8*>(qb + (size_t)(mt * 16 + l15) * HD + l4 * 8);
        f32x4 s[4];
#pragma unroll
        for (int nt = 0; nt < 4; ++nt) {
            f32x4 z = {};
            s[nt] = __builtin_amdgcn_mfma_f32_16x16x32_bf16(qf, kf[nt], z, 0, 0, 0);
        }

#pragma unroll
        for (int r = 0; r < 4; ++r) {
            int m = mt * 16 + l4 * 4 + r;
            float vals[4];
#pragma unroll
            for (int nt = 0; nt < 4; ++nt) {
                int n = nt * 16 + l15;
                float sv = s[nt][r];
                if (n < NTOK) {
                    if (m < NTOK) sv += add_h[m * NTOK + n];
                } else {
                    sv = -1e30f;
                }
                vals[nt] = sv;
            }
            float mx = fmaxf(fmaxf(vals[0], vals[1]), fmaxf(vals[2], vals[3]));
            mx = fmaxf(mx, __shfl_xor(mx, 1));
            mx = fmaxf(mx, __shfl_xor(mx, 2));
            mx = fmaxf(mx, __shfl_xor(mx, 4));
            mx = fmaxf(mx, __shfl_xor(mx, 8));
            float e0 = __expf(vals[0] - mx);
            float e1 = __expf(vals[1] - mx);
            float e2 = __expf(vals[2] - mx);
            float e3 = __expf(vals[3] - mx);
            float sum = (e0 + e1) + (e2 + e3);
            sum += __shfl_xor(sum, 1);
            sum += __shfl_xor(sum, 2);
            sum += __shfl_xor(sum, 4);
            sum += __shfl_xor(sum, 8);
            float inv = 1.0f / sum;
            float ev[4] = {e0, e1, e2, e3};
#pragma unroll
            for (int nt = 0; nt < 4; ++nt) {
                int lp = (l4 * 4 + r) + 16 * ((nt & 1) * 2 + (l15 >> 3));
                ps[wave][nt >> 1][lp][l15 & 7] = (__bf16)(ev[nt] * inv);
            }
        }

        f32x4 o[2] = {};
#pragma unroll
        for (int kb2 = 0; kb2 < 2; ++kb2) {
            bf16x8 ap = *reinterpret_cast<const bf16x8*>(&ps[wave][kb2][lane][0]);
#pragma unroll
            for (int dt = 0; dt < 2; ++dt) {
                int d = dt * 16 + l15;
                bf16x8 bv = *reinterpret_cast<const bf16x8*>(
                    &vt[wave][d * 64 + ((kb2 * 32 + l4 * 8) ^ ((l15 & 7) << 3))]);
                o[dt] = __builtin_amdgcn_mfma_f32_16x16x32_bf16(ap, bv, o[dt], 0, 0, 0);
            }
        }
#pragma unroll
        for (int dt = 0; dt < 2; ++dt) {
            int col = h * HD + dt * 16 + l15;
#pragma unroll
            for (int r = 0; r < 4; ++r) {
                int tok = mt * 16 + l4 * 4 + r;
                if (tok < NTOK)
                    attnout[((size_t)b * NTOK + tok) * CDIM + col] = (__bf16)o[dt][r];
            }
        }
    }
}

// ---------------- K3: out projection (unchanged) ----------------

__global__ __launch_bounds__(256, 3) void out_proj(
    const __bf16* __restrict__ A, const __bf16* __restrict__ WoutT,
    const float* __restrict__ bout, float* __restrict__ out)
{
    __shared__ __attribute__((aligned(16))) __bf16 as[4 * 12 * 512];   // frags [mt][kb][slot][8]
    const int blk = blockIdx.x, tid = threadIdx.x;
    const int wave = tid >> 6, lane = tid & 63;
    const int l15 = lane & 15, l4 = lane >> 4;

    const __bf16* Ab = A + (size_t)blk * 64 * CDIM;
    for (int i = tid; i < 64 * CDIM / 8; i += 256) {
        int4 ld = reinterpret_cast<const int4*>(Ab)[i];
        int e = i * 8;
        int row = e / CDIM, c = e % CDIM;
        int mt = row >> 4, kb = c >> 5;
        int lp = (row & 15) + 16 * ((c & 31) >> 3);
        int slot = lp ^ (kb & 7);
        *reinterpret_cast<int4*>(&as[((mt * 12 + kb) * 64 + slot) * 8]) = ld;
    }
    __syncthreads();

    f32x4 acc[6][4] = {};
    for (int kb = 0; kb < 12; ++kb) {
        int slot = lane ^ (kb & 7);
        bf16x8 af[4];
#pragma unroll
        for (int mt = 0; mt < 4; ++mt)
            af[mt] = *reinterpret_cast<const bf16x8*>(&as[((mt * 12 + kb) * 64 + slot) * 8]);
#pragma unroll
        for (int j = 0; j < 6; ++j) {
            int col = (wave * 6 + j) * 16 + l15;
            bf16x8 bf = *reinterpret_cast<const bf16x8*>(WoutT + (size_t)col * CDIM + kb * 32 + l4 * 8);
#pragma unroll
            for (int mt = 0; mt < 4; ++mt)
                acc[j][mt] = __builtin_amdgcn_mfma_f32_16x16x32_bf16(af[mt], bf, acc[j][mt], 0, 0, 0);
        }
    }
#pragma unroll
    for (int j = 0; j < 6; ++j) {
        int col = (wave * 6 + j) * 16 + l15;
        float bias = bout[col];
#pragma unroll
        for (int mt = 0; mt < 4; ++mt) {
#pragma unroll
            for (int r = 0; r < 4; ++r) {
                size_t row = (size_t)blk * 64 + mt * 16 + l4 * 4 + r;
                out[row * CDIM + col] = acc[j][mt][r] + bias;
            }
        }
    }
}

// ---------------- launch ----------------

extern "C" void kernel_launch(void* const* d_in, const int* in_sizes, int n_in,
                              void* d_out, int out_size, void* d_ws, size_t ws_size,
                              hipStream_t stream) {
    (void)n_in; (void)out_size; (void)ws_size;
    const float* x    = (const float*)d_in[0];
    const float* mask = (const float*)d_in[1];
    const float* Wqkv = (const float*)d_in[2];
    const float* bqkv = (const float*)d_in[3];
    const float* Wout = (const float*)d_in[4];
    const float* bout = (const float*)d_in[5];
    const float* rpb  = (const float*)d_in[6];
    const int*   rel  = (const int*)d_in[7];

    const int B = in_sizes[0] / (NTOK * CDIM);   // 4096
    const int M = B * NTOK;                      // 200704

    char* ws = (char*)d_ws;
    __bf16* WqkvT   = (__bf16*)(ws + OFF_WQKVT);
    __bf16* WoutT   = (__bf16*)(ws + OFF_WOUTT);
    float*  addend  = (float*)(ws + OFF_ADDEND);
    __bf16* qkvb    = (__bf16*)(ws + OFF_QKVB);
    __bf16* xb      = (__bf16*)(ws + OFF_XB);       // aliases attnout (xb dead before attn writes)
    __bf16* attnout = (__bf16*)(ws + OFF_ATTNOUT);
    float*  out     = (float*)d_out;

    prep_weights<<<(NQKV * CDIM + 255) / 256, 256, 0, stream>>>(Wqkv, Wout, WqkvT, WoutT);
    prep_addend<<<(NWIN * HEADS * NTOK * NTOK + 255) / 256, 256, 0, stream>>>(rpb, rel, mask, addend);
    prep_xb<<<2048, 256, 0, stream>>>(x, xb, M * CDIM / 8);
    gemm_qkv<<<(M / 128) * (NQKV / 128), 256, 0, stream>>>(xb, WqkvT, bqkv, qkvb);
    attn<<<dim3(B, 3), 256, 0, stream>>>(qkvb, addend, attnout);
    out_proj<<<M / 64, 256, 0, stream>>>(attnout, WoutT, bout, out);
}

// Round 13
// 891.958 us; speedup vs baseline: 1.1438x; 1.0397x over previous
//
#include <hip/hip_runtime.h>

#define NTOK 49
#define CDIM 384
#define HEADS 12
#define HD 32
#define NWIN 64
#define NQKV 1152
#define SCALE 0.17677669529663687f  // 32^-0.5

typedef __attribute__((ext_vector_type(8))) __bf16 bf16x8;
typedef __attribute__((ext_vector_type(4))) float f32x4;

// workspace offsets (bytes), all 256-aligned
#define OFF_WQKVT   0ull                 // 1152*384 bf16 = 884736
#define OFF_WOUTT   884736ull            // 384*384 bf16  = 294912
#define OFF_RPBF    1179648ull           // 12*4*4*64*4 f32 = 196608
#define OFF_MASKF   1376256ull           // 64*4*4*64*4 f32 = 1048576 (both inside old addend region)
#define OFF_QKVB    8555520ull           // 3 tensors [B][12][49][32] bf16 = 462422016 total
#define OFF_ATTNOUT 470977536ull         // 200704*384 bf16 = 154140672
#define OFF_XB      OFF_ATTNOUT          // xb aliases attnout: xb dead before attn writes
// total ~625.1 MB

#define TSIZE 77070336ull                // per-tensor elems: 200704*384 = B*HEADS*NTOK*HD

__device__ __forceinline__ void async_copy16(__bf16* lds_dst, const __bf16* g_src) {
    __builtin_amdgcn_global_load_lds(
        (const __attribute__((address_space(1))) void*)g_src,
        (__attribute__((address_space(3))) void*)lds_dst,
        16, 0, 0);
}

// ---------------- prep kernels ----------------

__global__ void prep_weights(const float* __restrict__ Wqkv, const float* __restrict__ Wout,
                             __bf16* __restrict__ WqkvT, __bf16* __restrict__ WoutT) {
    int idx = blockIdx.x * 256 + threadIdx.x;
    if (idx < NQKV * CDIM) {
        int n = idx / CDIM, k = idx % CDIM;
        WqkvT[idx] = (__bf16)Wqkv[(size_t)k * NQKV + n];
    }
    if (idx < CDIM * CDIM) {
        int n = idx / CDIM, k = idx % CDIM;
        WoutT[idx] = (__bf16)Wout[(size_t)k * CDIM + n];
    }
}

// fragment-layout bias tables: rpbF[h][mt][nt][lane][r], maskF[w][mt][nt][lane][r]
__global__ void prep_frag(const float* __restrict__ rpb, const int* __restrict__ rel,
                          const float* __restrict__ mask,
                          float* __restrict__ rpbF, float* __restrict__ maskF) {
    int idx = blockIdx.x * 256 + threadIdx.x;
    if (idx < 49152) {
        int r = idx & 3, lane = (idx >> 2) & 63, nt = (idx >> 8) & 3, mt = (idx >> 10) & 3, h = idx >> 12;
        int m = mt * 16 + ((lane >> 4) << 2) + r, n = nt * 16 + (lane & 15);
        rpbF[idx] = (m < NTOK && n < NTOK) ? rpb[rel[m * NTOK + n] * HEADS + h] : 0.f;
    } else {
        int i2 = idx - 49152;
        if (i2 < 262144) {
            int r = i2 & 3, lane = (i2 >> 2) & 63, nt = (i2 >> 8) & 3, mt = (i2 >> 10) & 3, w = i2 >> 12;
            int m = mt * 16 + ((lane >> 4) << 2) + r, n = nt * 16 + (lane & 15);
            maskF[i2] = (m < NTOK && n < NTOK) ? mask[(size_t)w * NTOK * NTOK + m * NTOK + n] : 0.f;
        }
    }
}

// x fp32 -> bf16, streaming (8 elems / thread / iter)
__global__ __launch_bounds__(256) void prep_xb(const float* __restrict__ x,
                                               __bf16* __restrict__ xb, int total8) {
    int stride = gridDim.x * 256;
    for (int i = blockIdx.x * 256 + threadIdx.x; i < total8; i += stride) {
        float4 a = reinterpret_cast<const float4*>(x)[i * 2];
        float4 b = reinterpret_cast<const float4*>(x)[i * 2 + 1];
        union { __bf16 h[8]; uint4 u; } t;
        t.h[0] = (__bf16)a.x; t.h[1] = (__bf16)a.y; t.h[2] = (__bf16)a.z; t.h[3] = (__bf16)a.w;
        t.h[4] = (__bf16)b.x; t.h[5] = (__bf16)b.y; t.h[6] = (__bf16)b.z; t.h[7] = (__bf16)b.w;
        reinterpret_cast<uint4*>(xb)[i] = t.u;
    }
}

// ---------------- K1: qkv GEMM, m97 structure + XCD swizzle; head-blocked output ----------------
// __launch_bounds__(256,4): cap 128 unified regs (need ~132) -> allocator squeeze for 4 blocks/CU.
// If this spills (FETCH/WRITE balloon) revert to (256,3).

__global__ __launch_bounds__(256, 4) void gemm_qkv(
    const __bf16* __restrict__ xb, const __bf16* __restrict__ WqkvT,
    const float* __restrict__ bqkv, __bf16* __restrict__ qkvb)
{
    __shared__ __attribute__((aligned(16))) __bf16 smem[16384];  // A [0,8192), B [8192,16384); C overlays
    __bf16* As = smem;
    __bf16* Bs = smem + 8192;

    // bijective XCD-chunk swizzle: nwg = 14112 = 8 * 1764
    const int cpx  = 14112 >> 3;                     // 1764
    const int lid  = (blockIdx.x & 7) * cpx + (blockIdx.x >> 3);
    const int mblk = lid / 9, nblk = lid % 9;
    const int n0  = nblk * 128;
    const int bm0 = mblk * 128;

    const int tid = threadIdx.x;
    const int wave = tid >> 6, lane = tid & 63;
    const int l15 = lane & 15, l4 = lane >> 4;
    const int wr = wave >> 1, wc = wave & 1;

    f32x4 acc[4][4] = {};

    for (int k0 = 0; k0 < CDIM; k0 += 64) {
#pragma unroll
        for (int j = 0; j < 4; ++j) {
            int c = wave * 4 + j;
            int mt = c >> 1, kk = c & 1;
            const __bf16* sa = xb + (size_t)(bm0 + mt * 16 + l15) * CDIM + k0 + kk * 32 + l4 * 8;
            async_copy16(&As[c * 512], sa);
            const __bf16* sb = WqkvT + (size_t)(n0 + mt * 16 + l15) * CDIM + k0 + kk * 32 + l4 * 8;
            async_copy16(&Bs[c * 512], sb);
        }
        __syncthreads();

#pragma unroll
        for (int kk = 0; kk < 2; ++kk) {
            bf16x8 af[4], bf[4];
#pragma unroll
            for (int mi = 0; mi < 4; ++mi)
                af[mi] = *reinterpret_cast<const bf16x8*>(&As[((wr * 4 + mi) * 2 + kk) * 512 + lane * 8]);
#pragma unroll
            for (int ni = 0; ni < 4; ++ni)
                bf[ni] = *reinterpret_cast<const bf16x8*>(&Bs[((wc * 4 + ni) * 2 + kk) * 512 + lane * 8]);
#pragma unroll
            for (int mi = 0; mi < 4; ++mi)
#pragma unroll
                for (int ni = 0; ni < 4; ++ni)
                    acc[mi][ni] = __builtin_amdgcn_mfma_f32_16x16x32_bf16(af[mi], bf[ni], acc[mi][ni], 0, 0, 0);
        }
        __syncthreads();
    }

    const float scl = (n0 < CDIM) ? SCALE : 1.0f;
    float bias[4];
#pragma unroll
    for (int ni = 0; ni < 4; ++ni)
        bias[ni] = bqkv[n0 + wc * 64 + ni * 16 + l15];

    __bf16* Cs = smem;   // [128][128] bf16, byte ^= ((row>>2)&3)<<5
#pragma unroll
    for (int mi = 0; mi < 4; ++mi)
#pragma unroll
        for (int ni = 0; ni < 4; ++ni)
#pragma unroll
            for (int r = 0; r < 4; ++r) {
                int row = wr * 64 + mi * 16 + l4 * 4 + r;
                int col = wc * 64 + ni * 16 + l15;
                int byte = (row * 256 + col * 2) ^ (((row >> 2) & 3) << 5);
                *reinterpret_cast<__bf16*>(reinterpret_cast<char*>(Cs) + byte) =
                    (__bf16)((acc[mi][ni][r] + bias[ni]) * scl);
            }
    __syncthreads();

    // head-blocked scatter: tensor = n0/384; 128 cols = 4 heads h0..h0+3
    const int which = n0 / CDIM;
    const int h0    = (n0 % CDIM) >> 5;
    __bf16* tbase = qkvb + (size_t)which * TSIZE;
#pragma unroll
    for (int it = 0; it < 8; ++it) {
        int idx = it * 4096 + tid * 16;
        int row = idx >> 8, bcol = idx & 255;
        int sb = (row * 256 + bcol) ^ (((row >> 2) & 3) << 5);
        uint4 v = *reinterpret_cast<const uint4*>(reinterpret_cast<const char*>(Cs) + sb);
        int grow = bm0 + row;
        int b = grow / NTOK, tok = grow - b * NTOK;
        int col = bcol >> 1;                 // 0..127
        int h = h0 + (col >> 5), d = col & 31;
        *reinterpret_cast<uint4*>(&tbase[(((size_t)b * HEADS + h) * NTOK + tok) * HD + d]) = v;
    }
}

// ---------------- K2: attention (head-blocked reads; frag-layout bias tables) ----------------
// grid (B, 3): 256 thr = 4 waves; wave = one head. No barriers.

__global__ __launch_bounds__(256) void attn(
    const __bf16* __restrict__ qkvb, const float* __restrict__ rpbF,
    const float* __restrict__ maskF, __bf16* __restrict__ attnout)
{
    __shared__ __attribute__((aligned(16))) __bf16 vt[4][32 * 64];    // [wave][d][tok ^ ((d&7)<<3)] 4KB/wave
    __shared__ __attribute__((aligned(16))) __bf16 ps[4][2][64][8];   // [wave][kb][lane][8]
    const int b = blockIdx.x;
    const int tid = threadIdx.x;
    const int wave = tid >> 6, lane = tid & 63;
    const int l15 = lane & 15, l4 = lane >> 4;
    const int h = blockIdx.y * 4 + wave;
    const int w = b & (NWIN - 1);

    const size_t hoff = (((size_t)b * HEADS + h) * NTOK) * HD;
    const __bf16* qb = qkvb + hoff;
    const __bf16* kb = qkvb + TSIZE + hoff;
    const __bf16* vb = qkvb + 2 * TSIZE + hoff;
    const f32x4* rpbF4  = reinterpret_cast<const f32x4*>(rpbF);
    const f32x4* maskF4 = reinterpret_cast<const f32x4*>(maskF);

    // ---- stage V coalesced: lane loads v[tok][c8..c8+7], scatters transposed into vt ----
    {
        const int tokb = lane >> 2;         // 0..15
        const int c8   = (lane & 3) * 8;    // 0,8,16,24
#pragma unroll
        for (int i = 0; i < 4; ++i) {
            int tok = i * 16 + tokb;
            bf16x8 vv = *reinterpret_cast<const bf16x8*>(vb + (size_t)tok * HD + c8);
#pragma unroll
            for (int j = 0; j < 8; ++j) {
                int d = c8 + j;
                vt[wave][d * 64 + (tok ^ ((d & 7) << 3))] = vv[j];
            }
        }
    }

    bf16x8 kf[4];
#pragma unroll
    for (int nt = 0; nt < 4; ++nt)
        kf[nt] = *reinterpret_cast<const bf16x8*>(kb + (size_t)(nt * 16 + l15) * HD + l4 * 8);

    for (int mt = 0; mt < 4; ++mt) {
        bf16x8 qf = *reinterpret_cast<const bf16x8*>(qb + (size_t)(mt * 16 + l15) * HD + l4 * 8);

        // issue bias-table loads early (latency hides under S MFMAs)
        f32x4 rb[4], mb[4];
#pragma unroll
        for (int nt = 0; nt < 4; ++nt) {
            rb[nt] = rpbF4[((h * 4 + mt) * 4 + nt) * 64 + lane];
            mb[nt] = maskF4[((w * 4 + mt) * 4 + nt) * 64 + lane];
        }

        f32x4 s[4];
#pragma unroll
        for (int nt = 0; nt < 4; ++nt) {
            f32x4 z = {};
            s[nt] = __builtin_amdgcn_mfma_f32_16x16x32_bf16(qf, kf[nt], z, 0, 0, 0);
        }

#pragma unroll
        for (int r = 0; r < 4; ++r) {
            float vals[4];
#pragma unroll
            for (int nt = 0; nt < 4; ++nt) {
                int n = nt * 16 + l15;
                vals[nt] = (n < NTOK) ? (s[nt][r] + rb[nt][r] + mb[nt][r]) : -1e30f;
            }
            float mx = fmaxf(fmaxf(vals[0], vals[1]), fmaxf(vals[2], vals[3]));
            mx = fmaxf(mx, __shfl_xor(mx, 1));
            mx = fmaxf(mx, __shfl_xor(mx, 2));
            mx = fmaxf(mx, __shfl_xor(mx, 4));
            mx = fmaxf(mx, __shfl_xor(mx, 8));
            float e0 = __expf(vals[0] - mx);
            float e1 = __expf(vals[1] - mx);
            float e2 = __expf(vals[2] - mx);
            float e3 = __expf(vals[3] - mx);
            float sum = (e0 + e1) + (e2 + e3);
            sum += __shfl_xor(sum, 1);
            sum += __shfl_xor(sum, 2);
            sum += __shfl_xor(sum, 4);
            sum += __shfl_xor(sum, 8);
            float inv = 1.0f / sum;
            float ev[4] = {e0, e1, e2, e3};
#pragma unroll
            for (int nt = 0; nt < 4; ++nt) {
                int lp = (l4 * 4 + r) + 16 * ((nt & 1) * 2 + (l15 >> 3));
                ps[wave][nt >> 1][lp][l15 & 7] = (__bf16)(ev[nt] * inv);
            }
        }

        f32x4 o[2] = {};
#pragma unroll
        for (int kb2 = 0; kb2 < 2; ++kb2) {
            bf16x8 ap = *reinterpret_cast<const bf16x8*>(&ps[wave][kb2][lane][0]);
#pragma unroll
            for (int dt = 0; dt < 2; ++dt) {
                int d = dt * 16 + l15;
                bf16x8 bv = *reinterpret_cast<const bf16x8*>(
                    &vt[wave][d * 64 + ((kb2 * 32 + l4 * 8) ^ ((l15 & 7) << 3))]);
                o[dt] = __builtin_amdgcn_mfma_f32_16x16x32_bf16(ap, bv, o[dt], 0, 0, 0);
            }
        }
#pragma unroll
        for (int dt = 0; dt < 2; ++dt) {
            int col = h * HD + dt * 16 + l15;
#pragma unroll
            for (int r = 0; r < 4; ++r) {
                int tok = mt * 16 + l4 * 4 + r;
                if (tok < NTOK)
                    attnout[((size_t)b * NTOK + tok) * CDIM + col] = (__bf16)o[dt][r];
            }
        }
    }
}

// ---------------- K3: out projection (unchanged) ----------------

__global__ __launch_bounds__(256, 3) void out_proj(
    const __bf16* __restrict__ A, const __bf16* __restrict__ WoutT,
    const float* __restrict__ bout, float* __restrict__ out)
{
    __shared__ __attribute__((aligned(16))) __bf16 as[4 * 12 * 512];   // frags [mt][kb][slot][8]
    const int blk = blockIdx.x, tid = threadIdx.x;
    const int wave = tid >> 6, lane = tid & 63;
    const int l15 = lane & 15, l4 = lane >> 4;

    const __bf16* Ab = A + (size_t)blk * 64 * CDIM;
    for (int i = tid; i < 64 * CDIM / 8; i += 256) {
        int4 ld = reinterpret_cast<const int4*>(Ab)[i];
        int e = i * 8;
        int row = e / CDIM, c = e % CDIM;
        int mt = row >> 4, kb = c >> 5;
        int lp = (row & 15) + 16 * ((c & 31) >> 3);
        int slot = lp ^ (kb & 7);
        *reinterpret_cast<int4*>(&as[((mt * 12 + kb) * 64 + slot) * 8]) = ld;
    }
    __syncthreads();

    f32x4 acc[6][4] = {};
    for (int kb = 0; kb < 12; ++kb) {
        int slot = lane ^ (kb & 7);
        bf16x8 af[4];
#pragma unroll
        for (int mt = 0; mt < 4; ++mt)
            af[mt] = *reinterpret_cast<const bf16x8*>(&as[((mt * 12 + kb) * 64 + slot) * 8]);
#pragma unroll
        for (int j = 0; j < 6; ++j) {
            int col = (wave * 6 + j) * 16 + l15;
            bf16x8 bf = *reinterpret_cast<const bf16x8*>(WoutT + (size_t)col * CDIM + kb * 32 + l4 * 8);
#pragma unroll
            for (int mt = 0; mt < 4; ++mt)
                acc[j][mt] = __builtin_amdgcn_mfma_f32_16x16x32_bf16(af[mt], bf, acc[j][mt], 0, 0, 0);
        }
    }
#pragma unroll
    for (int j = 0; j < 6; ++j) {
        int col = (wave * 6 + j) * 16 + l15;
        float bias = bout[col];
#pragma unroll
        for (int mt = 0; mt < 4; ++mt) {
#pragma unroll
            for (int r = 0; r < 4; ++r) {
                size_t row = (size_t)blk * 64 + mt * 16 + l4 * 4 + r;
                out[row * CDIM + col] = acc[j][mt][r] + bias;
            }
        }
    }
}

// ---------------- launch ----------------

extern "C" void kernel_launch(void* const* d_in, const int* in_sizes, int n_in,
                              void* d_out, int out_size, void* d_ws, size_t ws_size,
                              hipStream_t stream) {
    (void)n_in; (void)out_size; (void)ws_size;
    const float* x    = (const float*)d_in[0];
    const float* mask = (const float*)d_in[1];
    const float* Wqkv = (const float*)d_in[2];
    const float* bqkv = (const float*)d_in[3];
    const float* Wout = (const float*)d_in[4];
    const float* bout = (const float*)d_in[5];
    const float* rpb  = (const float*)d_in[6];
    const int*   rel  = (const int*)d_in[7];

    const int B = in_sizes[0] / (NTOK * CDIM);   // 4096
    const int M = B * NTOK;                      // 200704

    char* ws = (char*)d_ws;
    __bf16* WqkvT   = (__bf16*)(ws + OFF_WQKVT);
    __bf16* WoutT   = (__bf16*)(ws + OFF_WOUTT);
    float*  rpbF    = (float*)(ws + OFF_RPBF);
    float*  maskF   = (float*)(ws + OFF_MASKF);
    __bf16* qkvb    = (__bf16*)(ws + OFF_QKVB);
    __bf16* xb      = (__bf16*)(ws + OFF_XB);       // aliases attnout (xb dead before attn writes)
    __bf16* attnout = (__bf16*)(ws + OFF_ATTNOUT);
    float*  out     = (float*)d_out;

    prep_weights<<<(NQKV * CDIM + 255) / 256, 256, 0, stream>>>(Wqkv, Wout, WqkvT, WoutT);
    prep_frag<<<(49152 + 262144) / 256, 256, 0, stream>>>(rpb, rel, mask, rpbF, maskF);
    prep_xb<<<2048, 256, 0, stream>>>(x, xb, M * CDIM / 8);
    gemm_qkv<<<(M / 128) * (NQKV / 128), 256, 0, stream>>>(xb, WqkvT, bqkv, qkvb);
    attn<<<dim3(B, 3), 256, 0, stream>>>(qkvb, rpbF, maskF, attnout);
    out_proj<<<M / 64, 256, 0, stream>>>(attnout, WoutT, bout, out);
}

// Round 14
// 828.144 us; speedup vs baseline: 1.2319x; 1.0771x over previous
//
#include <hip/hip_runtime.h>

#define NTOK 49
#define CDIM 384
#define HEADS 12
#define HD 32
#define NWIN 64
#define NQKV 1152
#define SCALE 0.17677669529663687f  // 32^-0.5

typedef __attribute__((ext_vector_type(8))) __bf16 bf16x8;
typedef __attribute__((ext_vector_type(4))) float f32x4;

// workspace offsets (bytes), all 256-aligned
#define OFF_WQKVT   0ull                 // 1152*384 bf16 = 884736
#define OFF_WOUTT   884736ull            // 384*384 bf16  = 294912
#define OFF_RPBF    1179648ull           // 12*4*4*64*4 f32 = 196608
#define OFF_MASKF   1376256ull           // 64*4*4*64*4 f32 = 1048576
#define OFF_QKVB    8555520ull           // 3 tensors [B][12][49][32] bf16 = 462422016 total
#define OFF_ATTNOUT 470977536ull         // 200704*384 bf16 = 154140672
#define OFF_XB      OFF_ATTNOUT          // xb aliases attnout: xb dead before attn writes
// total ~625.1 MB

#define TSIZE 77070336ull                // per-tensor elems: 200704*384 = B*HEADS*NTOK*HD

__device__ __forceinline__ void async_copy16(__bf16* lds_dst, const __bf16* g_src) {
    __builtin_amdgcn_global_load_lds(
        (const __attribute__((address_space(1))) void*)g_src,
        (__attribute__((address_space(3))) void*)lds_dst,
        16, 0, 0);
}

// ---------------- prep kernels ----------------

__global__ void prep_weights(const float* __restrict__ Wqkv, const float* __restrict__ Wout,
                             __bf16* __restrict__ WqkvT, __bf16* __restrict__ WoutT) {
    int idx = blockIdx.x * 256 + threadIdx.x;
    if (idx < NQKV * CDIM) {
        int n = idx / CDIM, k = idx % CDIM;
        WqkvT[idx] = (__bf16)Wqkv[(size_t)k * NQKV + n];
    }
    if (idx < CDIM * CDIM) {
        int n = idx / CDIM, k = idx % CDIM;
        WoutT[idx] = (__bf16)Wout[(size_t)k * CDIM + n];
    }
}

// fragment-layout bias tables: rpbF[h][mt][nt][lane][r], maskF[w][mt][nt][lane][r]
__global__ void prep_frag(const float* __restrict__ rpb, const int* __restrict__ rel,
                          const float* __restrict__ mask,
                          float* __restrict__ rpbF, float* __restrict__ maskF) {
    int idx = blockIdx.x * 256 + threadIdx.x;
    if (idx < 49152) {
        int r = idx & 3, lane = (idx >> 2) & 63, nt = (idx >> 8) & 3, mt = (idx >> 10) & 3, h = idx >> 12;
        int m = mt * 16 + ((lane >> 4) << 2) + r, n = nt * 16 + (lane & 15);
        rpbF[idx] = (m < NTOK && n < NTOK) ? rpb[rel[m * NTOK + n] * HEADS + h] : 0.f;
    } else {
        int i2 = idx - 49152;
        if (i2 < 262144) {
            int r = i2 & 3, lane = (i2 >> 2) & 63, nt = (i2 >> 8) & 3, mt = (i2 >> 10) & 3, w = i2 >> 12;
            int m = mt * 16 + ((lane >> 4) << 2) + r, n = nt * 16 + (lane & 15);
            maskF[i2] = (m < NTOK && n < NTOK) ? mask[(size_t)w * NTOK * NTOK + m * NTOK + n] : 0.f;
        }
    }
}

// x fp32 -> bf16, streaming (8 elems / thread / iter)
__global__ __launch_bounds__(256) void prep_xb(const float* __restrict__ x,
                                               __bf16* __restrict__ xb, int total8) {
    int stride = gridDim.x * 256;
    for (int i = blockIdx.x * 256 + threadIdx.x; i < total8; i += stride) {
        float4 a = reinterpret_cast<const float4*>(x)[i * 2];
        float4 b = reinterpret_cast<const float4*>(x)[i * 2 + 1];
        union { __bf16 h[8]; uint4 u; } t;
        t.h[0] = (__bf16)a.x; t.h[1] = (__bf16)a.y; t.h[2] = (__bf16)a.z; t.h[3] = (__bf16)a.w;
        t.h[4] = (__bf16)b.x; t.h[5] = (__bf16)b.y; t.h[6] = (__bf16)b.z; t.h[7] = (__bf16)b.w;
        reinterpret_cast<uint4*>(xb)[i] = t.u;
    }
}

// ---------------- K1: qkv GEMM, m97 structure + XCD swizzle; head-blocked output (unchanged) ----------------

__global__ __launch_bounds__(256, 4) void gemm_qkv(
    const __bf16* __restrict__ xb, const __bf16* __restrict__ WqkvT,
    const float* __restrict__ bqkv, __bf16* __restrict__ qkvb)
{
    __shared__ __attribute__((aligned(16))) __bf16 smem[16384];  // A [0,8192), B [8192,16384); C overlays
    __bf16* As = smem;
    __bf16* Bs = smem + 8192;

    // bijective XCD-chunk swizzle: nwg = 14112 = 8 * 1764
    const int cpx  = 14112 >> 3;                     // 1764
    const int lid  = (blockIdx.x & 7) * cpx + (blockIdx.x >> 3);
    const int mblk = lid / 9, nblk = lid % 9;
    const int n0  = nblk * 128;
    const int bm0 = mblk * 128;

    const int tid = threadIdx.x;
    const int wave = tid >> 6, lane = tid & 63;
    const int l15 = lane & 15, l4 = lane >> 4;
    const int wr = wave >> 1, wc = wave & 1;

    f32x4 acc[4][4] = {};

    for (int k0 = 0; k0 < CDIM; k0 += 64) {
#pragma unroll
        for (int j = 0; j < 4; ++j) {
            int c = wave * 4 + j;
            int mt = c >> 1, kk = c & 1;
            const __bf16* sa = xb + (size_t)(bm0 + mt * 16 + l15) * CDIM + k0 + kk * 32 + l4 * 8;
            async_copy16(&As[c * 512], sa);
            const __bf16* sb = WqkvT + (size_t)(n0 + mt * 16 + l15) * CDIM + k0 + kk * 32 + l4 * 8;
            async_copy16(&Bs[c * 512], sb);
        }
        __syncthreads();

#pragma unroll
        for (int kk = 0; kk < 2; ++kk) {
            bf16x8 af[4], bf[4];
#pragma unroll
            for (int mi = 0; mi < 4; ++mi)
                af[mi] = *reinterpret_cast<const bf16x8*>(&As[((wr * 4 + mi) * 2 + kk) * 512 + lane * 8]);
#pragma unroll
            for (int ni = 0; ni < 4; ++ni)
                bf[ni] = *reinterpret_cast<const bf16x8*>(&Bs[((wc * 4 + ni) * 2 + kk) * 512 + lane * 8]);
#pragma unroll
            for (int mi = 0; mi < 4; ++mi)
#pragma unroll
                for (int ni = 0; ni < 4; ++ni)
                    acc[mi][ni] = __builtin_amdgcn_mfma_f32_16x16x32_bf16(af[mi], bf[ni], acc[mi][ni], 0, 0, 0);
        }
        __syncthreads();
    }

    const float scl = (n0 < CDIM) ? SCALE : 1.0f;
    float bias[4];
#pragma unroll
    for (int ni = 0; ni < 4; ++ni)
        bias[ni] = bqkv[n0 + wc * 64 + ni * 16 + l15];

    __bf16* Cs = smem;   // [128][128] bf16, byte ^= ((row>>2)&3)<<5
#pragma unroll
    for (int mi = 0; mi < 4; ++mi)
#pragma unroll
        for (int ni = 0; ni < 4; ++ni)
#pragma unroll
            for (int r = 0; r < 4; ++r) {
                int row = wr * 64 + mi * 16 + l4 * 4 + r;
                int col = wc * 64 + ni * 16 + l15;
                int byte = (row * 256 + col * 2) ^ (((row >> 2) & 3) << 5);
                *reinterpret_cast<__bf16*>(reinterpret_cast<char*>(Cs) + byte) =
                    (__bf16)((acc[mi][ni][r] + bias[ni]) * scl);
            }
    __syncthreads();

    // head-blocked scatter: tensor = n0/384; 128 cols = 4 heads h0..h0+3
    const int which = n0 / CDIM;
    const int h0    = (n0 % CDIM) >> 5;
    __bf16* tbase = qkvb + (size_t)which * TSIZE;
#pragma unroll
    for (int it = 0; it < 8; ++it) {
        int idx = it * 4096 + tid * 16;
        int row = idx >> 8, bcol = idx & 255;
        int sb = (row * 256 + bcol) ^ (((row >> 2) & 3) << 5);
        uint4 v = *reinterpret_cast<const uint4*>(reinterpret_cast<const char*>(Cs) + sb);
        int grow = bm0 + row;
        int b = grow / NTOK, tok = grow - b * NTOK;
        int col = bcol >> 1;                 // 0..127
        int h = h0 + (col >> 5), d = col & 31;
        *reinterpret_cast<uint4*>(&tbase[(((size_t)b * HEADS + h) * NTOK + tok) * HD + d]) = v;
    }
}

// ---------------- K2: attention (unchanged from r13) ----------------

__global__ __launch_bounds__(256) void attn(
    const __bf16* __restrict__ qkvb, const float* __restrict__ rpbF,
    const float* __restrict__ maskF, __bf16* __restrict__ attnout)
{
    __shared__ __attribute__((aligned(16))) __bf16 vt[4][32 * 64];    // [wave][d][tok ^ ((d&7)<<3)] 4KB/wave
    __shared__ __attribute__((aligned(16))) __bf16 ps[4][2][64][8];   // [wave][kb][lane][8]
    const int b = blockIdx.x;
    const int tid = threadIdx.x;
    const int wave = tid >> 6, lane = tid & 63;
    const int l15 = lane & 15, l4 = lane >> 4;
    const int h = blockIdx.y * 4 + wave;
    const int w = b & (NWIN - 1);

    const size_t hoff = (((size_t)b * HEADS + h) * NTOK) * HD;
    const __bf16* qb = qkvb + hoff;
    const __bf16* kb = qkvb + TSIZE + hoff;
    const __bf16* vb = qkvb + 2 * TSIZE + hoff;
    const f32x4* rpbF4  = reinterpret_cast<const f32x4*>(rpbF);
    const f32x4* maskF4 = reinterpret_cast<const f32x4*>(maskF);

    // ---- stage V coalesced: lane loads v[tok][c8..c8+7], scatters transposed into vt ----
    {
        const int tokb = lane >> 2;         // 0..15
        const int c8   = (lane & 3) * 8;    // 0,8,16,24
#pragma unroll
        for (int i = 0; i < 4; ++i) {
            int tok = i * 16 + tokb;
            bf16x8 vv = *reinterpret_cast<const bf16x8*>(vb + (size_t)tok * HD + c8);
#pragma unroll
            for (int j = 0; j < 8; ++j) {
                int d = c8 + j;
                vt[wave][d * 64 + (tok ^ ((d & 7) << 3))] = vv[j];
            }
        }
    }

    bf16x8 kf[4];
#pragma unroll
    for (int nt = 0; nt < 4; ++nt)
        kf[nt] = *reinterpret_cast<const bf16x8*>(kb + (size_t)(nt * 16 + l15) * HD + l4 * 8);

    for (int mt = 0; mt < 4; ++mt) {
        bf16x8 qf = *reinterpret_cast<const bf16x8*>(qb + (size_t)(mt * 16 + l15) * HD + l4 * 8);

        // issue bias-table loads early (latency hides under S MFMAs)
        f32x4 rb[4], mb[4];
#pragma unroll
        for (int nt = 0; nt < 4; ++nt) {
            rb[nt] = rpbF4[((h * 4 + mt) * 4 + nt) * 64 + lane];
            mb[nt] = maskF4[((w * 4 + mt) * 4 + nt) * 64 + lane];
        }

        f32x4 s[4];
#pragma unroll
        for (int nt = 0; nt < 4; ++nt) {
            f32x4 z = {};
            s[nt] = __builtin_amdgcn_mfma_f32_16x16x32_bf16(qf, kf[nt], z, 0, 0, 0);
        }

#pragma unroll
        for (int r = 0; r < 4; ++r) {
            float vals[4];
#pragma unroll
            for (int nt = 0; nt < 4; ++nt) {
                int n = nt * 16 + l15;
                vals[nt] = (n < NTOK) ? (s[nt][r] + rb[nt][r] + mb[nt][r]) : -1e30f;
            }
            float mx = fmaxf(fmaxf(vals[0], vals[1]), fmaxf(vals[2], vals[3]));
            mx = fmaxf(mx, __shfl_xor(mx, 1));
            mx = fmaxf(mx, __shfl_xor(mx, 2));
            mx = fmaxf(mx, __shfl_xor(mx, 4));
            mx = fmaxf(mx, __shfl_xor(mx, 8));
            float e0 = __expf(vals[0] - mx);
            float e1 = __expf(vals[1] - mx);
            float e2 = __expf(vals[2] - mx);
            float e3 = __expf(vals[3] - mx);
            float sum = (e0 + e1) + (e2 + e3);
            sum += __shfl_xor(sum, 1);
            sum += __shfl_xor(sum, 2);
            sum += __shfl_xor(sum, 4);
            sum += __shfl_xor(sum, 8);
            float inv = 1.0f / sum;
            float ev[4] = {e0, e1, e2, e3};
#pragma unroll
            for (int nt = 0; nt < 4; ++nt) {
                int lp = (l4 * 4 + r) + 16 * ((nt & 1) * 2 + (l15 >> 3));
                ps[wave][nt >> 1][lp][l15 & 7] = (__bf16)(ev[nt] * inv);
            }
        }

        f32x4 o[2] = {};
#pragma unroll
        for (int kb2 = 0; kb2 < 2; ++kb2) {
            bf16x8 ap = *reinterpret_cast<const bf16x8*>(&ps[wave][kb2][lane][0]);
#pragma unroll
            for (int dt = 0; dt < 2; ++dt) {
                int d = dt * 16 + l15;
                bf16x8 bv = *reinterpret_cast<const bf16x8*>(
                    &vt[wave][d * 64 + ((kb2 * 32 + l4 * 8) ^ ((l15 & 7) << 3))]);
                o[dt] = __builtin_amdgcn_mfma_f32_16x16x32_bf16(ap, bv, o[dt], 0, 0, 0);
            }
        }
#pragma unroll
        for (int dt = 0; dt < 2; ++dt) {
            int col = h * HD + dt * 16 + l15;
#pragma unroll
            for (int r = 0; r < 4; ++r) {
                int tok = mt * 16 + l4 * 4 + r;
                if (tok < NTOK)
                    attnout[((size_t)b * NTOK + tok) * CDIM + col] = (__bf16)o[dt][r];
            }
        }
    }
}

// ---------------- K3: out projection, m97 structure (gemm_qkv clone) ----------------
// [M=200704,384] @ [384,384] + bout -> fp32 out. grid 1568 m x 3 n = 4704 blocks (= 8*588).
// A=attnout staged async; B=WoutT staged async; direct fp32 C stores.

__global__ __launch_bounds__(256, 4) void out_proj(
    const __bf16* __restrict__ A, const __bf16* __restrict__ WoutT,
    const float* __restrict__ bout, float* __restrict__ out)
{
    __shared__ __attribute__((aligned(16))) __bf16 smem[16384];  // A [0,8192), B [8192,16384)
    __bf16* As = smem;
    __bf16* Bs = smem + 8192;

    // bijective XCD-chunk swizzle: nwg = 4704 = 8 * 588; n-fastest for A-tile L2 reuse
    const int cpx  = 4704 >> 3;                      // 588
    const int lid  = (blockIdx.x & 7) * cpx + (blockIdx.x >> 3);
    const int mblk = lid / 3, nblk = lid % 3;
    const int n0  = nblk * 128;
    const int bm0 = mblk * 128;

    const int tid = threadIdx.x;
    const int wave = tid >> 6, lane = tid & 63;
    const int l15 = lane & 15, l4 = lane >> 4;
    const int wr = wave >> 1, wc = wave & 1;

    f32x4 acc[4][4] = {};

    for (int k0 = 0; k0 < CDIM; k0 += 64) {
#pragma unroll
        for (int j = 0; j < 4; ++j) {
            int c = wave * 4 + j;
            int mt = c >> 1, kk = c & 1;
            const __bf16* sa = A + (size_t)(bm0 + mt * 16 + l15) * CDIM + k0 + kk * 32 + l4 * 8;
            async_copy16(&As[c * 512], sa);
            const __bf16* sb = WoutT + (size_t)(n0 + mt * 16 + l15) * CDIM + k0 + kk * 32 + l4 * 8;
            async_copy16(&Bs[c * 512], sb);
        }
        __syncthreads();

#pragma unroll
        for (int kk = 0; kk < 2; ++kk) {
            bf16x8 af[4], bf[4];
#pragma unroll
            for (int mi = 0; mi < 4; ++mi)
                af[mi] = *reinterpret_cast<const bf16x8*>(&As[((wr * 4 + mi) * 2 + kk) * 512 + lane * 8]);
#pragma unroll
            for (int ni = 0; ni < 4; ++ni)
                bf[ni] = *reinterpret_cast<const bf16x8*>(&Bs[((wc * 4 + ni) * 2 + kk) * 512 + lane * 8]);
#pragma unroll
            for (int mi = 0; mi < 4; ++mi)
#pragma unroll
                for (int ni = 0; ni < 4; ++ni)
                    acc[mi][ni] = __builtin_amdgcn_mfma_f32_16x16x32_bf16(af[mi], bf[ni], acc[mi][ni], 0, 0, 0);
        }
        __syncthreads();
    }

    float bias[4];
#pragma unroll
    for (int ni = 0; ni < 4; ++ni)
        bias[ni] = bout[n0 + wc * 64 + ni * 16 + l15];

#pragma unroll
    for (int mi = 0; mi < 4; ++mi)
#pragma unroll
        for (int ni = 0; ni < 4; ++ni)
#pragma unroll
            for (int r = 0; r < 4; ++r) {
                size_t row = (size_t)bm0 + wr * 64 + mi * 16 + l4 * 4 + r;
                int col = n0 + wc * 64 + ni * 16 + l15;
                out[row * CDIM + col] = acc[mi][ni][r] + bias[ni];
            }
}

// ---------------- launch ----------------

extern "C" void kernel_launch(void* const* d_in, const int* in_sizes, int n_in,
                              void* d_out, int out_size, void* d_ws, size_t ws_size,
                              hipStream_t stream) {
    (void)n_in; (void)out_size; (void)ws_size;
    const float* x    = (const float*)d_in[0];
    const float* mask = (const float*)d_in[1];
    const float* Wqkv = (const float*)d_in[2];
    const float* bqkv = (const float*)d_in[3];
    const float* Wout = (const float*)d_in[4];
    const float* bout = (const float*)d_in[5];
    const float* rpb  = (const float*)d_in[6];
    const int*   rel  = (const int*)d_in[7];

    const int B = in_sizes[0] / (NTOK * CDIM);   // 4096
    const int M = B * NTOK;                      // 200704

    char* ws = (char*)d_ws;
    __bf16* WqkvT   = (__bf16*)(ws + OFF_WQKVT);
    __bf16* WoutT   = (__bf16*)(ws + OFF_WOUTT);
    float*  rpbF    = (float*)(ws + OFF_RPBF);
    float*  maskF   = (float*)(ws + OFF_MASKF);
    __bf16* qkvb    = (__bf16*)(ws + OFF_QKVB);
    __bf16* xb      = (__bf16*)(ws + OFF_XB);       // aliases attnout (xb dead before attn writes)
    __bf16* attnout = (__bf16*)(ws + OFF_ATTNOUT);
    float*  out     = (float*)d_out;

    prep_weights<<<(NQKV * CDIM + 255) / 256, 256, 0, stream>>>(Wqkv, Wout, WqkvT, WoutT);
    prep_frag<<<(49152 + 262144) / 256, 256, 0, stream>>>(rpb, rel, mask, rpbF, maskF);
    prep_xb<<<2048, 256, 0, stream>>>(x, xb, M * CDIM / 8);
    gemm_qkv<<<(M / 128) * (NQKV / 128), 256, 0, stream>>>(xb, WqkvT, bqkv, qkvb);
    attn<<<dim3(B, 3), 256, 0, stream>>>(qkvb, rpbF, maskF, attnout);
    out_proj<<<(M / 128) * 3, 256, 0, stream>>>(attnout, WoutT, bout, out);
}